// Round 1
// baseline (787.688 us; speedup 1.0000x reference)
//
#include <hip/hip_runtime.h>
#include <cstdint>
#include <cstddef>

// ---- problem constants ----
#define B_   2
#define N_   2048
#define C_   768
#define H_   12
#define D_   64
#define HID_ 3072
#define BH_  24          // B*H
#define MM   4096        // B*N rows

typedef __attribute__((ext_vector_type(8))) short s16x8;   // 8 bf16 (4 VGPR)
typedef __attribute__((ext_vector_type(4))) short s16x4;   // 4 bf16 (2 VGPR)
typedef __attribute__((ext_vector_type(4))) float f32x4;

__device__ __forceinline__ short f2bf(float f) {           // fp32 -> bf16 RNE
  uint32_t u = __float_as_uint(f);
  u += 0x7fffu + ((u >> 16) & 1u);
  return (short)(u >> 16);
}

__device__ __forceinline__ void gl_lds16(const void* g, void* l) {
  // async global->LDS, 16B/lane, LDS dest = wave-uniform base + lane*16
  __builtin_amdgcn_global_load_lds((const __attribute__((address_space(1))) void*)g,
                                   (__attribute__((address_space(3))) void*)l,
                                   16, 0, 0);
}

// ---------------- fp32 -> bf16 weight convert ----------------
__global__ __launch_bounds__(256) void k_cvt(const float* __restrict__ in,
                                             short* __restrict__ out, int n) {
  int i = (blockIdx.x * 256 + threadIdx.x) * 4;
  if (i >= n) return;
  float4 v = *(const float4*)(in + i);
  s16x4 o;
  o[0] = f2bf(v.x); o[1] = f2bf(v.y); o[2] = f2bf(v.z); o[3] = f2bf(v.w);
  *(s16x4*)(out + i) = o;
}

// ---------------- LayerNorm (fp32 in, bf16 out), one row per block ----------
__global__ __launch_bounds__(256) void k_ln(const float* __restrict__ x,
                                            const float* __restrict__ w,
                                            const float* __restrict__ b,
                                            short* __restrict__ out) {
  const int row = blockIdx.x, t = threadIdx.x;
  const float* xr = x + (size_t)row * C_;
  float a0 = xr[t], a1 = xr[t + 256], a2 = xr[t + 512];
  float s = a0 + a1 + a2;
  float q = a0 * a0 + a1 * a1 + a2 * a2;
  #pragma unroll
  for (int off = 32; off >= 1; off >>= 1) {
    s += __shfl_xor(s, off);
    q += __shfl_xor(q, off);
  }
  __shared__ float ps[4], pq[4];
  if ((t & 63) == 0) { ps[t >> 6] = s; pq[t >> 6] = q; }
  __syncthreads();
  s = ps[0] + ps[1] + ps[2] + ps[3];
  q = pq[0] + pq[1] + pq[2] + pq[3];
  const float mean = s * (1.0f / C_);
  const float var  = q * (1.0f / C_) - mean * mean;
  const float rs   = rsqrtf(var + 1e-5f);
  short* orow = out + (size_t)row * C_;
  orow[t]       = f2bf((a0 - mean) * rs * w[t]       + b[t]);
  orow[t + 256] = f2bf((a1 - mean) * rs * w[t + 256] + b[t + 256]);
  orow[t + 512] = f2bf((a2 - mean) * rs * w[t + 512] + b[t + 512]);
}

// ---------------- 128x128 bf16 MFMA GEMM core (m97 structure) ---------------
// C[m][n] = sum_k A[m][k] * W[n][k]   (both row-major, stride K, B^T form)
__device__ __forceinline__ void gemm_core(const short* __restrict__ A,
                                          const short* __restrict__ Bw,
                                          int K, short* As, short* Bs,
                                          f32x4 acc[4][4]) {
  const int tid = threadIdx.x, lane = tid & 63, wid = tid >> 6;
  const int wm = wid & 1, wn = wid >> 1;
  const int l15 = lane & 15, quad = lane >> 4;
  const size_t bm = (size_t)blockIdx.x * 128, bn = (size_t)blockIdx.y * 128;
  #pragma unroll
  for (int mi = 0; mi < 4; ++mi)
    #pragma unroll
    for (int ni = 0; ni < 4; ++ni)
      acc[mi][ni] = (f32x4){0.f, 0.f, 0.f, 0.f};
  const int rrow = lane >> 2;        // row within 16-row staging group
  const int rcol = (lane & 3) * 8;   // bf16-element col offset (16B chunks)
  for (int k0 = 0; k0 < K; k0 += 32) {
    #pragma unroll
    for (int i = 0; i < 2; ++i) {
      const int rg = wid * 2 + i;    // 16-row group 0..7
      gl_lds16(A  + (bm + rg * 16 + rrow) * (size_t)K + k0 + rcol, As + rg * 512);
      gl_lds16(Bw + (bn + rg * 16 + rrow) * (size_t)K + k0 + rcol, Bs + rg * 512);
    }
    __syncthreads();                 // drains vmcnt(0): global_load_lds done
    s16x8 af[4], bf[4];
    #pragma unroll
    for (int mi = 0; mi < 4; ++mi)
      af[mi] = *(const s16x8*)(As + (wm * 64 + mi * 16 + l15) * 32 + quad * 8);
    #pragma unroll
    for (int ni = 0; ni < 4; ++ni)
      bf[ni] = *(const s16x8*)(Bs + (wn * 64 + ni * 16 + l15) * 32 + quad * 8);
    #pragma unroll
    for (int mi = 0; mi < 4; ++mi)
      #pragma unroll
      for (int ni = 0; ni < 4; ++ni)
        acc[mi][ni] = __builtin_amdgcn_mfma_f32_16x16x32_bf16(af[mi], bf[ni],
                                                              acc[mi][ni], 0, 0, 0);
    __syncthreads();
  }
}

// ---------------- QKV GEMM: [4096,768] x [2304,768]^T -----------------------
// epilogue: +bias, q*=D^-0.5, scatter to q/k/v [B,H,N,D] bf16
__global__ __launch_bounds__(256) void k_gemm_qkv(const short* __restrict__ A,
    const short* __restrict__ W, const float* __restrict__ bias,
    short* __restrict__ qb, short* __restrict__ kb, short* __restrict__ vb) {
  __shared__ short As[4096], Bs[4096];
  f32x4 acc[4][4];
  gemm_core(A, W, C_, As, Bs, acc);
  const int lane = threadIdx.x & 63, wid = threadIdx.x >> 6;
  const int wm = wid & 1, wn = wid >> 1, quad = lane >> 4, l15 = lane & 15;
  const int m0 = blockIdx.x * 128 + wm * 64;
  const int n0 = blockIdx.y * 128 + wn * 64;
  #pragma unroll
  for (int ni = 0; ni < 4; ++ni) {
    const int n = n0 + ni * 16 + l15;
    const int s = n / C_, rem = n % C_;     // s: 0=q 1=k 2=v
    const int h = rem >> 6, d = rem & 63;
    short* dst = (s == 0) ? qb : (s == 1) ? kb : vb;
    const float scale = (s == 0) ? 0.125f : 1.0f;
    const float bv = bias[n];
    #pragma unroll
    for (int mi = 0; mi < 4; ++mi)
      #pragma unroll
      for (int r = 0; r < 4; ++r) {
        const int m = m0 + mi * 16 + quad * 4 + r;
        const int bb = m >> 11, pos = m & 2047;
        dst[(((size_t)bb * H_ + h) * N_ + pos) * D_ + d] =
            f2bf((acc[mi][ni][r] + bv) * scale);
      }
  }
}

// ---------------- V transpose: [BH,N,D] -> [BH,D,N] -------------------------
__global__ __launch_bounds__(256) void k_trans_v(const short* __restrict__ v,
                                                 short* __restrict__ vt) {
  __shared__ short t[64][68];
  const int bh = blockIdx.y;
  const int p0 = blockIdx.x * 64;
  #pragma unroll
  for (int i = 0; i < 16; ++i) {
    const int idx = threadIdx.x + i * 256;
    const int r = idx >> 6, c = idx & 63;    // r=pos, c=d
    t[r][c] = v[((size_t)bh * N_ + p0 + r) * D_ + c];
  }
  __syncthreads();
  #pragma unroll
  for (int i = 0; i < 16; ++i) {
    const int idx = threadIdx.x + i * 256;
    const int r = idx >> 6, c = idx & 63;    // r=d, c=pos
    vt[((size_t)bh * D_ + r) * N_ + p0 + c] = t[c][r];
  }
}

// ---------------- Flash attention, S^T orientation --------------------------
// block = 4 waves x 16 q rows = 64 q rows; j-tiles of 64 keys.
// S^T = K * Q^T (16x16x32): softmax stats per-lane (col q = lane&15).
// PV via 16x16x16: C/D layout == B-operand layout, so softmaxed S^T regs are
// P^T fragments directly (no LDS round-trip for P).
__global__ __launch_bounds__(256) void k_attn(const short* __restrict__ qb,
    const short* __restrict__ kb, const short* __restrict__ vtb,
    const float* __restrict__ alibi, const int* __restrict__ mask,
    short* __restrict__ aout) {
  __shared__ short Ks[64 * 72], Vs[64 * 72];   // +8 bf16 row pad: 2-way only
  const int tid = threadIdx.x, lane = tid & 63, wid = tid >> 6;
  const int quad = lane >> 4, l15 = lane & 15;
  const int bh = blockIdx.y, bb = bh / H_, hh = bh % H_;
  const int qg = blockIdx.x * 64 + wid * 16 + l15;   // global query row

  const short* qrow = qb + ((size_t)bh * N_ + qg) * D_;
  const s16x8 qf0 = *(const s16x8*)(qrow + quad * 8);        // d 0..31 slice
  const s16x8 qf1 = *(const s16x8*)(qrow + 32 + quad * 8);   // d 32..63 slice

  f32x4 oacc[4];
  #pragma unroll
  for (int i = 0; i < 4; ++i) oacc[i] = (f32x4){0.f, 0.f, 0.f, 0.f};
  float mrun = -1e30f, lrun = 0.f;

  const float* arow = alibi + ((size_t)bh * N_ + qg) * N_;
  const int* mrow = mask + bb * N_;

  for (int jt = 0; jt < N_; jt += 64) {
    // ---- stage K tile [64j][64d] and V^T tile [64d][64j] (padded rows) ----
    #pragma unroll
    for (int c = 0; c < 2; ++c) {
      const int idx = tid + c * 256;
      const int row = idx >> 3, col = (idx & 7) * 8;
      *(int4*)(&Ks[row * 72 + col]) =
          *(const int4*)(kb + ((size_t)bh * N_ + jt + row) * D_ + col);
      *(int4*)(&Vs[row * 72 + col]) =
          *(const int4*)(vtb + ((size_t)bh * D_ + row) * N_ + jt + col);
    }
    __syncthreads();

    // ---- mask (block-uniform in j): skip fully-padded tiles ----
    int4 mk[4];
    int anyvalid = 0;
    #pragma unroll
    for (int ji = 0; ji < 4; ++ji) {
      mk[ji] = *(const int4*)(mrow + jt + ji * 16 + quad * 4);
      if (!(mk[ji].x && mk[ji].y && mk[ji].z && mk[ji].w)) anyvalid = 1;
    }
    if (!__any(anyvalid)) { __syncthreads(); continue; }

    // ---- S^T[j][q] = K * Q^T ----
    f32x4 s[4];
    #pragma unroll
    for (int ji = 0; ji < 4; ++ji) {
      const s16x8 ka = *(const s16x8*)(&Ks[(ji * 16 + l15) * 72 + quad * 8]);
      const s16x8 kc = *(const s16x8*)(&Ks[(ji * 16 + l15) * 72 + 32 + quad * 8]);
      f32x4 z = (f32x4){0.f, 0.f, 0.f, 0.f};
      z = __builtin_amdgcn_mfma_f32_16x16x32_bf16(ka, qf0, z, 0, 0, 0);
      s[ji] = __builtin_amdgcn_mfma_f32_16x16x32_bf16(kc, qf1, z, 0, 0, 0);
    }

    // ---- alibi + mask + online softmax (per-lane row stats, 2 shuffles) ----
    float p[4][4];
    float mt = -1e30f;
    #pragma unroll
    for (int ji = 0; ji < 4; ++ji) {
      const float4 al = *(const float4*)(arow + jt + ji * 16 + quad * 4);
      float v0 = s[ji][0] + al.x; if (mk[ji].x) v0 = -1e30f;
      float v1 = s[ji][1] + al.y; if (mk[ji].y) v1 = -1e30f;
      float v2 = s[ji][2] + al.z; if (mk[ji].z) v2 = -1e30f;
      float v3 = s[ji][3] + al.w; if (mk[ji].w) v3 = -1e30f;
      p[ji][0] = v0; p[ji][1] = v1; p[ji][2] = v2; p[ji][3] = v3;
      mt = fmaxf(mt, fmaxf(fmaxf(v0, v1), fmaxf(v2, v3)));
    }
    mt = fmaxf(mt, __shfl_xor(mt, 16));
    mt = fmaxf(mt, __shfl_xor(mt, 32));
    const float mnew = fmaxf(mrun, mt);
    const float scl = __expf(mrun - mnew);
    float psum = 0.f;
    s16x4 pf[4];
    #pragma unroll
    for (int ji = 0; ji < 4; ++ji)
      #pragma unroll
      for (int r = 0; r < 4; ++r) {
        const float e = __expf(p[ji][r] - mnew);
        psum += e;
        pf[ji][r] = f2bf(e);
      }
    psum += __shfl_xor(psum, 16);
    psum += __shfl_xor(psum, 32);
    lrun = lrun * scl + psum;
    mrun = mnew;
    #pragma unroll
    for (int i = 0; i < 4; ++i) oacc[i] *= scl;

    // ---- O^T[d][q] += V^T * P^T  (P^T = pf, free reinterpret) ----
    #pragma unroll
    for (int ji = 0; ji < 4; ++ji)
      #pragma unroll
      for (int ni = 0; ni < 4; ++ni) {
        const s16x4 vf = *(const s16x4*)(&Vs[(ni * 16 + l15) * 72 + ji * 16 + quad * 4]);
        oacc[ni] = __builtin_amdgcn_mfma_f32_16x16x16bf16_1k(vf, pf[ji],
                                                             oacc[ni], 0, 0, 0);
      }
    __syncthreads();
  }

  const float inv = 1.0f / lrun;
  short* orow = aout + ((size_t)bb * N_ + qg) * C_ + hh * D_;
  #pragma unroll
  for (int ni = 0; ni < 4; ++ni)
    #pragma unroll
    for (int r = 0; r < 4; ++r)
      orow[ni * 16 + quad * 4 + r] = f2bf(oacc[ni][r] * inv);
}

// ---------------- proj GEMM + bias + residual (fp32 out) --------------------
__global__ __launch_bounds__(256) void k_gemm_proj(const short* __restrict__ A,
    const short* __restrict__ W, const float* __restrict__ bias,
    const float* __restrict__ xres, float* __restrict__ hout) {
  __shared__ short As[4096], Bs[4096];
  f32x4 acc[4][4];
  gemm_core(A, W, C_, As, Bs, acc);
  const int lane = threadIdx.x & 63, wid = threadIdx.x >> 6;
  const int wm = wid & 1, wn = wid >> 1, quad = lane >> 4, l15 = lane & 15;
  const int m0 = blockIdx.x * 128 + wm * 64;
  const int n0 = blockIdx.y * 128 + wn * 64;
  #pragma unroll
  for (int ni = 0; ni < 4; ++ni) {
    const int n = n0 + ni * 16 + l15;
    const float bv = bias[n];
    #pragma unroll
    for (int mi = 0; mi < 4; ++mi)
      #pragma unroll
      for (int r = 0; r < 4; ++r) {
        const int m = m0 + mi * 16 + quad * 4 + r;
        hout[(size_t)m * C_ + n] = acc[mi][ni][r] + bv + xres[(size_t)m * C_ + n];
      }
  }
}

// ---------------- fc1 GEMM + bias + exact GELU (bf16 out) -------------------
__global__ __launch_bounds__(256) void k_gemm_fc1(const short* __restrict__ A,
    const short* __restrict__ W, const float* __restrict__ bias,
    short* __restrict__ hid) {
  __shared__ short As[4096], Bs[4096];
  f32x4 acc[4][4];
  gemm_core(A, W, C_, As, Bs, acc);
  const int lane = threadIdx.x & 63, wid = threadIdx.x >> 6;
  const int wm = wid & 1, wn = wid >> 1, quad = lane >> 4, l15 = lane & 15;
  const int m0 = blockIdx.x * 128 + wm * 64;
  const int n0 = blockIdx.y * 128 + wn * 64;
  #pragma unroll
  for (int ni = 0; ni < 4; ++ni) {
    const int n = n0 + ni * 16 + l15;
    const float bv = bias[n];
    #pragma unroll
    for (int mi = 0; mi < 4; ++mi)
      #pragma unroll
      for (int r = 0; r < 4; ++r) {
        const int m = m0 + mi * 16 + quad * 4 + r;
        const float v = acc[mi][ni][r] + bv;
        const float g = 0.5f * v * (1.0f + erff(v * 0.7071067811865475f));
        hid[(size_t)m * HID_ + n] = f2bf(g);
      }
  }
}

// ---------------- fc2 GEMM + bias; writes (t+t, t) --------------------------
__global__ __launch_bounds__(256) void k_gemm_fc2(const short* __restrict__ A,
    const short* __restrict__ W, const float* __restrict__ bias,
    float* __restrict__ out) {
  __shared__ short As[4096], Bs[4096];
  f32x4 acc[4][4];
  gemm_core(A, W, HID_, As, Bs, acc);
  const int lane = threadIdx.x & 63, wid = threadIdx.x >> 6;
  const int wm = wid & 1, wn = wid >> 1, quad = lane >> 4, l15 = lane & 15;
  const int m0 = blockIdx.x * 128 + wm * 64;
  const int n0 = blockIdx.y * 128 + wn * 64;
  #pragma unroll
  for (int ni = 0; ni < 4; ++ni) {
    const int n = n0 + ni * 16 + l15;
    const float bv = bias[n];
    #pragma unroll
    for (int mi = 0; mi < 4; ++mi)
      #pragma unroll
      for (int r = 0; r < 4; ++r) {
        const int m = m0 + mi * 16 + quad * 4 + r;
        const float t = acc[mi][ni][r] + bv;
        out[(size_t)m * C_ + n] = t + t;                          // output 0
        out[(size_t)MM * C_ + (size_t)m * C_ + n] = t;            // output 1
      }
  }
}

extern "C" void kernel_launch(void* const* d_in, const int* in_sizes, int n_in,
                              void* d_out, int out_size, void* d_ws, size_t ws_size,
                              hipStream_t stream) {
  (void)in_sizes; (void)n_in; (void)out_size; (void)ws_size;
  const float* x      = (const float*)d_in[0];
  const int*   mask   = (const int*)  d_in[1];   // bool normalized to int32
  const float* alibi  = (const float*)d_in[2];
  const float* qkv_w  = (const float*)d_in[3];
  const float* qkv_b  = (const float*)d_in[4];
  const float* proj_w = (const float*)d_in[5];
  const float* proj_b = (const float*)d_in[6];
  const float* n1w    = (const float*)d_in[7];
  const float* n1b    = (const float*)d_in[8];
  const float* n2w    = (const float*)d_in[9];
  const float* n2b    = (const float*)d_in[10];
  const float* fc1_w  = (const float*)d_in[11];
  const float* fc1_b  = (const float*)d_in[12];
  const float* fc2_w  = (const float*)d_in[13];
  const float* fc2_b  = (const float*)d_in[14];
  float* out = (float*)d_out;

  // workspace layout (~83.4 MB)
  char* ws = (char*)d_ws;
  size_t off = 0;
  auto alloc = [&](size_t bytes) -> void* {
    void* p = ws + off;
    off += (bytes + 255) & ~(size_t)255;
    return p;
  };
  short* wq   = (short*)alloc((size_t)3 * C_ * C_ * 2);      // qkv_w bf16
  short* wp   = (short*)alloc((size_t)C_ * C_ * 2);          // proj_w bf16
  short* wf1  = (short*)alloc((size_t)HID_ * C_ * 2);        // fc1_w bf16
  short* wf2  = (short*)alloc((size_t)C_ * HID_ * 2);        // fc2_w bf16
  short* xln  = (short*)alloc((size_t)MM * C_ * 2);          // ln1 out (reused as ln2 out)
  short* qb   = (short*)alloc((size_t)BH_ * N_ * D_ * 2);
  short* kb   = (short*)alloc((size_t)BH_ * N_ * D_ * 2);
  short* vb   = (short*)alloc((size_t)BH_ * N_ * D_ * 2);    // reused as attn out
  short* vtb  = (short*)alloc((size_t)BH_ * D_ * N_ * 2);
  float* h    = (float*)alloc((size_t)MM * C_ * 4);
  short* hid  = (short*)alloc((size_t)MM * HID_ * 2);
  short* hln  = xln;    // xln dead after qkv gemm
  short* aout = vb;     // vb dead after transpose

  k_cvt<<<3 * C_ * C_ / 1024, 256, 0, stream>>>(qkv_w, wq, 3 * C_ * C_);
  k_cvt<<<C_ * C_ / 1024, 256, 0, stream>>>(proj_w, wp, C_ * C_);
  k_cvt<<<HID_ * C_ / 1024, 256, 0, stream>>>(fc1_w, wf1, HID_ * C_);
  k_cvt<<<C_ * HID_ / 1024, 256, 0, stream>>>(fc2_w, wf2, C_ * HID_);

  k_ln<<<MM, 256, 0, stream>>>(x, n1w, n1b, xln);
  k_gemm_qkv<<<dim3(MM / 128, 3 * C_ / 128), 256, 0, stream>>>(xln, wq, qkv_b,
                                                               qb, kb, vb);
  k_trans_v<<<dim3(N_ / 64, BH_), 256, 0, stream>>>(vb, vtb);
  k_attn<<<dim3(N_ / 64, BH_), 256, 0, stream>>>(qb, kb, vtb, alibi, mask, aout);
  k_gemm_proj<<<dim3(MM / 128, C_ / 128), 256, 0, stream>>>(aout, wp, proj_b, x, h);
  k_ln<<<MM, 256, 0, stream>>>(h, n2w, n2b, hln);
  k_gemm_fc1<<<dim3(MM / 128, HID_ / 128), 256, 0, stream>>>(hln, wf1, fc1_b, hid);
  k_gemm_fc2<<<dim3(MM / 128, C_ / 128), 256, 0, stream>>>(hid, wf2, fc2_b, out);
}

// Round 2
// 749.403 us; speedup vs baseline: 1.0511x; 1.0511x over previous
//
#include <hip/hip_runtime.h>
#include <cstdint>
#include <cstddef>

// ---- problem constants ----
#define B_   2
#define N_   2048
#define C_   768
#define H_   12
#define D_   64
#define HID_ 3072
#define BH_  24          // B*H
#define MM   4096        // B*N rows

typedef __attribute__((ext_vector_type(8))) short s16x8;   // 8 bf16 (4 VGPR)
typedef __attribute__((ext_vector_type(4))) short s16x4;   // 4 bf16 (2 VGPR)
typedef __attribute__((ext_vector_type(4))) float f32x4;

__device__ __forceinline__ short f2bf(float f) {           // fp32 -> bf16 RNE
  uint32_t u = __float_as_uint(f);
  u += 0x7fffu + ((u >> 16) & 1u);
  return (short)(u >> 16);
}

__device__ __forceinline__ void gl_lds16(const void* g, void* l) {
  // async global->LDS, 16B/lane, LDS dest = wave-uniform base + lane*16
  __builtin_amdgcn_global_load_lds((const __attribute__((address_space(1))) void*)g,
                                   (__attribute__((address_space(3))) void*)l,
                                   16, 0, 0);
}

__device__ __forceinline__ float gelu_tanh(float v) {
  // max |err| vs exact erf-GELU ~1e-3, well under tolerance; ~8 VALU vs ~30 for erff
  const float z  = 0.7978845608f * v * (1.0f + 0.044715f * v * v);
  const float e  = __expf(-2.0f * fabsf(z));
  const float th = copysignf((1.0f - e) / (1.0f + e), z);
  return 0.5f * v * (1.0f + th);
}

// ---------------- fp32 -> bf16 weight convert (4 segments, 1 launch) --------
__global__ __launch_bounds__(256) void k_cvt4(
    const float* __restrict__ a, short* __restrict__ oa,
    const float* __restrict__ b, short* __restrict__ ob,
    const float* __restrict__ c, short* __restrict__ oc,
    const float* __restrict__ d, short* __restrict__ od) {
  // segment block counts: qkv 1728, proj 576, fc1 2304, fc2 2304 (x1024 elems)
  const int blk = blockIdx.x;
  const float* in; short* out; int base;
  if (blk < 1728)      { in = a; out = oa; base = blk; }
  else if (blk < 2304) { in = b; out = ob; base = blk - 1728; }
  else if (blk < 4608) { in = c; out = oc; base = blk - 2304; }
  else                 { in = d; out = od; base = blk - 4608; }
  const int i = (base * 256 + threadIdx.x) * 4;
  float4 v = *(const float4*)(in + i);
  s16x4 o;
  o[0] = f2bf(v.x); o[1] = f2bf(v.y); o[2] = f2bf(v.z); o[3] = f2bf(v.w);
  *(s16x4*)(out + i) = o;
}

// ---------------- LayerNorm (fp32 in, bf16 out), one row per block ----------
__global__ __launch_bounds__(256) void k_ln(const float* __restrict__ x,
                                            const float* __restrict__ w,
                                            const float* __restrict__ b,
                                            short* __restrict__ out) {
  const int row = blockIdx.x, t = threadIdx.x;
  const float* xr = x + (size_t)row * C_;
  float a0 = xr[t], a1 = xr[t + 256], a2 = xr[t + 512];
  float s = a0 + a1 + a2;
  float q = a0 * a0 + a1 * a1 + a2 * a2;
  #pragma unroll
  for (int off = 32; off >= 1; off >>= 1) {
    s += __shfl_xor(s, off);
    q += __shfl_xor(q, off);
  }
  __shared__ float ps[4], pq[4];
  if ((t & 63) == 0) { ps[t >> 6] = s; pq[t >> 6] = q; }
  __syncthreads();
  s = ps[0] + ps[1] + ps[2] + ps[3];
  q = pq[0] + pq[1] + pq[2] + pq[3];
  const float mean = s * (1.0f / C_);
  const float var  = q * (1.0f / C_) - mean * mean;
  const float rs   = rsqrtf(var + 1e-5f);
  short* orow = out + (size_t)row * C_;
  orow[t]       = f2bf((a0 - mean) * rs * w[t]       + b[t]);
  orow[t + 256] = f2bf((a1 - mean) * rs * w[t + 256] + b[t + 256]);
  orow[t + 512] = f2bf((a2 - mean) * rs * w[t + 512] + b[t + 512]);
}

// ---------------- 128x128 bf16 MFMA GEMM core (m97 structure) ---------------
// acc[m][n] = sum_{k in [kbeg,kend)} A[m][k] * W[n][k]; both row-major, ld=ldk
__device__ __forceinline__ void gemm_core(const short* __restrict__ A,
                                          const short* __restrict__ Bw,
                                          int ldk, int kbeg, int kend,
                                          short* As, short* Bs,
                                          f32x4 acc[4][4]) {
  const int tid = threadIdx.x, lane = tid & 63, wid = tid >> 6;
  const int wm = wid & 1, wn = wid >> 1;
  const int l15 = lane & 15, quad = lane >> 4;
  const size_t bm = (size_t)blockIdx.x * 128, bn = (size_t)blockIdx.y * 128;
  #pragma unroll
  for (int mi = 0; mi < 4; ++mi)
    #pragma unroll
    for (int ni = 0; ni < 4; ++ni)
      acc[mi][ni] = (f32x4){0.f, 0.f, 0.f, 0.f};
  const int rrow = lane >> 2;        // row within 16-row staging group
  const int rcol = (lane & 3) * 8;   // bf16-element col offset (16B chunks)
  for (int k0 = kbeg; k0 < kend; k0 += 32) {
    #pragma unroll
    for (int i = 0; i < 2; ++i) {
      const int rg = wid * 2 + i;    // 16-row group 0..7
      gl_lds16(A  + (bm + rg * 16 + rrow) * (size_t)ldk + k0 + rcol, As + rg * 512);
      gl_lds16(Bw + (bn + rg * 16 + rrow) * (size_t)ldk + k0 + rcol, Bs + rg * 512);
    }
    __syncthreads();                 // drains vmcnt(0): global_load_lds done
    s16x8 af[4], bf[4];
    #pragma unroll
    for (int mi = 0; mi < 4; ++mi)
      af[mi] = *(const s16x8*)(As + (wm * 64 + mi * 16 + l15) * 32 + quad * 8);
    #pragma unroll
    for (int ni = 0; ni < 4; ++ni)
      bf[ni] = *(const s16x8*)(Bs + (wn * 64 + ni * 16 + l15) * 32 + quad * 8);
    #pragma unroll
    for (int mi = 0; mi < 4; ++mi)
      #pragma unroll
      for (int ni = 0; ni < 4; ++ni)
        acc[mi][ni] = __builtin_amdgcn_mfma_f32_16x16x32_bf16(af[mi], bf[ni],
                                                              acc[mi][ni], 0, 0, 0);
    __syncthreads();
  }
}

// ---------------- QKV GEMM: [4096,768] x [2304,768]^T -----------------------
__global__ __launch_bounds__(256) void k_gemm_qkv(const short* __restrict__ A,
    const short* __restrict__ W, const float* __restrict__ bias,
    short* __restrict__ qb, short* __restrict__ kb, short* __restrict__ vb) {
  __shared__ short As[4096], Bs[4096];
  f32x4 acc[4][4];
  gemm_core(A, W, C_, 0, C_, As, Bs, acc);
  const int lane = threadIdx.x & 63, wid = threadIdx.x >> 6;
  const int wm = wid & 1, wn = wid >> 1, quad = lane >> 4, l15 = lane & 15;
  const int m0 = blockIdx.x * 128 + wm * 64;
  const int n0 = blockIdx.y * 128 + wn * 64;
  #pragma unroll
  for (int ni = 0; ni < 4; ++ni) {
    const int n = n0 + ni * 16 + l15;
    const int s = n / C_, rem = n % C_;     // s: 0=q 1=k 2=v
    const int h = rem >> 6, d = rem & 63;
    short* dst = (s == 0) ? qb : (s == 1) ? kb : vb;
    const float scale = (s == 0) ? 0.125f : 1.0f;
    const float bv = bias[n];
    #pragma unroll
    for (int mi = 0; mi < 4; ++mi)
      #pragma unroll
      for (int r = 0; r < 4; ++r) {
        const int m = m0 + mi * 16 + quad * 4 + r;
        const int bb = m >> 11, pos = m & 2047;
        dst[(((size_t)bb * H_ + h) * N_ + pos) * D_ + d] =
            f2bf((acc[mi][ni][r] + bv) * scale);
      }
  }
}

// ---------------- V transpose: [BH,N,D] -> [BH,D,N] -------------------------
__global__ __launch_bounds__(256) void k_trans_v(const short* __restrict__ v,
                                                 short* __restrict__ vt) {
  __shared__ short t[64][68];
  const int bh = blockIdx.y;
  const int p0 = blockIdx.x * 64;
  #pragma unroll
  for (int i = 0; i < 16; ++i) {
    const int idx = threadIdx.x + i * 256;
    const int r = idx >> 6, c = idx & 63;    // r=pos, c=d
    t[r][c] = v[((size_t)bh * N_ + p0 + r) * D_ + c];
  }
  __syncthreads();
  #pragma unroll
  for (int i = 0; i < 16; ++i) {
    const int idx = threadIdx.x + i * 256;
    const int r = idx >> 6, c = idx & 63;    // r=d, c=pos
    vt[((size_t)bh * D_ + r) * N_ + p0 + c] = t[c][r];
  }
}

// ---------------- Flash attention, S^T orientation --------------------------
__global__ __launch_bounds__(256) void k_attn(const short* __restrict__ qb,
    const short* __restrict__ kb, const short* __restrict__ vtb,
    const float* __restrict__ alibi, const int* __restrict__ mask,
    short* __restrict__ aout) {
  __shared__ short Ks[64 * 72], Vs[64 * 72];   // +8 bf16 row pad: 2-way only
  const int tid = threadIdx.x, lane = tid & 63, wid = tid >> 6;
  const int quad = lane >> 4, l15 = lane & 15;
  const int bh = blockIdx.y, bb = bh / H_, hh = bh % H_;
  const int qg = blockIdx.x * 64 + wid * 16 + l15;   // global query row

  const short* qrow = qb + ((size_t)bh * N_ + qg) * D_;
  const s16x8 qf0 = *(const s16x8*)(qrow + quad * 8);        // d 0..31 slice
  const s16x8 qf1 = *(const s16x8*)(qrow + 32 + quad * 8);   // d 32..63 slice

  f32x4 oacc[4];
  #pragma unroll
  for (int i = 0; i < 4; ++i) oacc[i] = (f32x4){0.f, 0.f, 0.f, 0.f};
  float mrun = -1e30f, lrun = 0.f;

  const float* arow = alibi + ((size_t)bh * N_ + qg) * N_;
  const int* mrow = mask + bb * N_;

  for (int jt = 0; jt < N_; jt += 64) {
    // ---- mask first (block-uniform in j): skip fully-padded tiles, incl staging
    int4 mk[4];
    int anyvalid = 0;
    #pragma unroll
    for (int ji = 0; ji < 4; ++ji) {
      mk[ji] = *(const int4*)(mrow + jt + ji * 16 + quad * 4);
      if (!(mk[ji].x && mk[ji].y && mk[ji].z && mk[ji].w)) anyvalid = 1;
    }
    if (!__any(anyvalid)) continue;     // uniform across block (same j set per wave)

    // ---- stage K tile [64j][64d] and V^T tile [64d][64j] (padded rows) ----
    #pragma unroll
    for (int c = 0; c < 2; ++c) {
      const int idx = tid + c * 256;
      const int row = idx >> 3, col = (idx & 7) * 8;
      *(int4*)(&Ks[row * 72 + col]) =
          *(const int4*)(kb + ((size_t)bh * N_ + jt + row) * D_ + col);
      *(int4*)(&Vs[row * 72 + col]) =
          *(const int4*)(vtb + ((size_t)bh * D_ + row) * N_ + jt + col);
    }
    __syncthreads();

    // ---- S^T[j][q] = K * Q^T ----
    f32x4 s[4];
    #pragma unroll
    for (int ji = 0; ji < 4; ++ji) {
      const s16x8 ka = *(const s16x8*)(&Ks[(ji * 16 + l15) * 72 + quad * 8]);
      const s16x8 kc = *(const s16x8*)(&Ks[(ji * 16 + l15) * 72 + 32 + quad * 8]);
      f32x4 z = (f32x4){0.f, 0.f, 0.f, 0.f};
      z = __builtin_amdgcn_mfma_f32_16x16x32_bf16(ka, qf0, z, 0, 0, 0);
      s[ji] = __builtin_amdgcn_mfma_f32_16x16x32_bf16(kc, qf1, z, 0, 0, 0);
    }

    // ---- alibi + mask + online softmax (per-lane row stats, 2 shuffles) ----
    float p[4][4];
    float mt = -1e30f;
    #pragma unroll
    for (int ji = 0; ji < 4; ++ji) {
      const float4 al = *(const float4*)(arow + jt + ji * 16 + quad * 4);
      float v0 = s[ji][0] + al.x; if (mk[ji].x) v0 = -1e30f;
      float v1 = s[ji][1] + al.y; if (mk[ji].y) v1 = -1e30f;
      float v2 = s[ji][2] + al.z; if (mk[ji].z) v2 = -1e30f;
      float v3 = s[ji][3] + al.w; if (mk[ji].w) v3 = -1e30f;
      p[ji][0] = v0; p[ji][1] = v1; p[ji][2] = v2; p[ji][3] = v3;
      mt = fmaxf(mt, fmaxf(fmaxf(v0, v1), fmaxf(v2, v3)));
    }
    mt = fmaxf(mt, __shfl_xor(mt, 16));
    mt = fmaxf(mt, __shfl_xor(mt, 32));
    const float mnew = fmaxf(mrun, mt);
    const float scl = __expf(mrun - mnew);
    float psum = 0.f;
    s16x4 pf[4];
    #pragma unroll
    for (int ji = 0; ji < 4; ++ji)
      #pragma unroll
      for (int r = 0; r < 4; ++r) {
        const float e = __expf(p[ji][r] - mnew);
        psum += e;
        pf[ji][r] = f2bf(e);
      }
    psum += __shfl_xor(psum, 16);
    psum += __shfl_xor(psum, 32);
    lrun = lrun * scl + psum;
    mrun = mnew;
    #pragma unroll
    for (int i = 0; i < 4; ++i) oacc[i] *= scl;

    // ---- O^T[d][q] += V^T * P^T  (P^T = pf regs, free reinterpret) ----
    #pragma unroll
    for (int ji = 0; ji < 4; ++ji)
      #pragma unroll
      for (int ni = 0; ni < 4; ++ni) {
        const s16x4 vf = *(const s16x4*)(&Vs[(ni * 16 + l15) * 72 + ji * 16 + quad * 4]);
        oacc[ni] = __builtin_amdgcn_mfma_f32_16x16x16bf16_1k(vf, pf[ji],
                                                             oacc[ni], 0, 0, 0);
      }
    __syncthreads();
  }

  const float inv = 1.0f / lrun;
  short* orow = aout + ((size_t)bb * N_ + qg) * C_ + hh * D_;
  #pragma unroll
  for (int ni = 0; ni < 4; ++ni)
    #pragma unroll
    for (int r = 0; r < 4; ++r)
      orow[ni * 16 + quad * 4 + r] = f2bf(oacc[ni][r] * inv);
}

// ---------------- proj GEMM split-K=2: partials (no bias) -------------------
__global__ __launch_bounds__(256) void k_gemm_projs(const short* __restrict__ A,
    const short* __restrict__ W, float* __restrict__ part) {
  __shared__ short As[4096], Bs[4096];
  f32x4 acc[4][4];
  const int z = blockIdx.z;
  gemm_core(A, W, C_, z * 384, z * 384 + 384, As, Bs, acc);
  const int lane = threadIdx.x & 63, wid = threadIdx.x >> 6;
  const int wm = wid & 1, wn = wid >> 1, quad = lane >> 4, l15 = lane & 15;
  const int m0 = blockIdx.x * 128 + wm * 64;
  const int n0 = blockIdx.y * 128 + wn * 64;
  float* pz = part + (size_t)z * MM * C_;
  #pragma unroll
  for (int ni = 0; ni < 4; ++ni) {
    const int n = n0 + ni * 16 + l15;
    #pragma unroll
    for (int mi = 0; mi < 4; ++mi)
      #pragma unroll
      for (int r = 0; r < 4; ++r) {
        const int m = m0 + mi * 16 + quad * 4 + r;
        pz[(size_t)m * C_ + n] = acc[mi][ni][r];
      }
  }
}

// ---------------- proj reduce: sum partials + bias + residual ---------------
__global__ __launch_bounds__(256) void k_proj_red(const float* __restrict__ p,
    const float* __restrict__ bias, const float* __restrict__ xres,
    float* __restrict__ hout) {
  const int i = (blockIdx.x * 256 + threadIdx.x) * 4;
  const float4 s0 = *(const float4*)(p + i);
  const float4 s1 = *(const float4*)(p + (size_t)MM * C_ + i);
  const float4 bv = *(const float4*)(bias + (i % C_));
  const float4 xr = *(const float4*)(xres + i);
  float4 o;
  o.x = s0.x + s1.x + bv.x + xr.x;
  o.y = s0.y + s1.y + bv.y + xr.y;
  o.z = s0.z + s1.z + bv.z + xr.z;
  o.w = s0.w + s1.w + bv.w + xr.w;
  *(float4*)(hout + i) = o;
}

// ---------------- fc1 GEMM + bias + tanh-GELU (bf16 out) --------------------
__global__ __launch_bounds__(256) void k_gemm_fc1(const short* __restrict__ A,
    const short* __restrict__ W, const float* __restrict__ bias,
    short* __restrict__ hid) {
  __shared__ short As[4096], Bs[4096];
  f32x4 acc[4][4];
  gemm_core(A, W, C_, 0, C_, As, Bs, acc);
  const int lane = threadIdx.x & 63, wid = threadIdx.x >> 6;
  const int wm = wid & 1, wn = wid >> 1, quad = lane >> 4, l15 = lane & 15;
  const int m0 = blockIdx.x * 128 + wm * 64;
  const int n0 = blockIdx.y * 128 + wn * 64;
  #pragma unroll
  for (int ni = 0; ni < 4; ++ni) {
    const int n = n0 + ni * 16 + l15;
    const float bv = bias[n];
    #pragma unroll
    for (int mi = 0; mi < 4; ++mi)
      #pragma unroll
      for (int r = 0; r < 4; ++r) {
        const int m = m0 + mi * 16 + quad * 4 + r;
        hid[(size_t)m * HID_ + n] = f2bf(gelu_tanh(acc[mi][ni][r] + bv));
      }
  }
}

// ---------------- fc2 GEMM split-K=4: partials (no bias) --------------------
__global__ __launch_bounds__(256) void k_gemm_fc2s(const short* __restrict__ A,
    const short* __restrict__ W, float* __restrict__ part) {
  __shared__ short As[4096], Bs[4096];
  f32x4 acc[4][4];
  const int z = blockIdx.z;
  gemm_core(A, W, HID_, z * 768, z * 768 + 768, As, Bs, acc);
  const int lane = threadIdx.x & 63, wid = threadIdx.x >> 6;
  const int wm = wid & 1, wn = wid >> 1, quad = lane >> 4, l15 = lane & 15;
  const int m0 = blockIdx.x * 128 + wm * 64;
  const int n0 = blockIdx.y * 128 + wn * 64;
  float* pz = part + (size_t)z * MM * C_;
  #pragma unroll
  for (int ni = 0; ni < 4; ++ni) {
    const int n = n0 + ni * 16 + l15;
    #pragma unroll
    for (int mi = 0; mi < 4; ++mi)
      #pragma unroll
      for (int r = 0; r < 4; ++r) {
        const int m = m0 + mi * 16 + quad * 4 + r;
        pz[(size_t)m * C_ + n] = acc[mi][ni][r];
      }
  }
}

// ---------------- fc2 reduce: t = sum+bias; writes (t+t, t) -----------------
__global__ __launch_bounds__(256) void k_fc2_red(const float* __restrict__ p,
    const float* __restrict__ bias, float* __restrict__ out) {
  const int i = (blockIdx.x * 256 + threadIdx.x) * 4;
  const float4 s0 = *(const float4*)(p + i);
  const float4 s1 = *(const float4*)(p + (size_t)MM * C_ + i);
  const float4 s2 = *(const float4*)(p + (size_t)2 * MM * C_ + i);
  const float4 s3 = *(const float4*)(p + (size_t)3 * MM * C_ + i);
  const float4 bv = *(const float4*)(bias + (i % C_));
  float4 t, t2;
  t.x = s0.x + s1.x + s2.x + s3.x + bv.x;  t2.x = t.x + t.x;
  t.y = s0.y + s1.y + s2.y + s3.y + bv.y;  t2.y = t.y + t.y;
  t.z = s0.z + s1.z + s2.z + s3.z + bv.z;  t2.z = t.z + t.z;
  t.w = s0.w + s1.w + s2.w + s3.w + bv.w;  t2.w = t.w + t.w;
  *(float4*)(out + i) = t2;
  *(float4*)(out + (size_t)MM * C_ + i) = t;
}

extern "C" void kernel_launch(void* const* d_in, const int* in_sizes, int n_in,
                              void* d_out, int out_size, void* d_ws, size_t ws_size,
                              hipStream_t stream) {
  (void)in_sizes; (void)n_in; (void)out_size; (void)ws_size;
  const float* x      = (const float*)d_in[0];
  const int*   mask   = (const int*)  d_in[1];   // bool normalized to int32
  const float* alibi  = (const float*)d_in[2];
  const float* qkv_w  = (const float*)d_in[3];
  const float* qkv_b  = (const float*)d_in[4];
  const float* proj_w = (const float*)d_in[5];
  const float* proj_b = (const float*)d_in[6];
  const float* n1w    = (const float*)d_in[7];
  const float* n1b    = (const float*)d_in[8];
  const float* n2w    = (const float*)d_in[9];
  const float* n2b    = (const float*)d_in[10];
  const float* fc1_w  = (const float*)d_in[11];
  const float* fc1_b  = (const float*)d_in[12];
  const float* fc2_w  = (const float*)d_in[13];
  const float* fc2_b  = (const float*)d_in[14];
  float* out = (float*)d_out;

  char* ws = (char*)d_ws;
  size_t off = 0;
  auto alloc = [&](size_t bytes) -> void* {
    void* p = ws + off;
    off += (bytes + 255) & ~(size_t)255;
    return p;
  };
  short* wq   = (short*)alloc((size_t)3 * C_ * C_ * 2);      // qkv_w bf16
  short* wp   = (short*)alloc((size_t)C_ * C_ * 2);          // proj_w bf16
  short* wf1  = (short*)alloc((size_t)HID_ * C_ * 2);        // fc1_w bf16
  short* wf2  = (short*)alloc((size_t)C_ * HID_ * 2);        // fc2_w bf16
  short* xln  = (short*)alloc((size_t)MM * C_ * 2);          // ln1 out (reused as ln2 out)
  short* qb   = (short*)alloc((size_t)BH_ * N_ * D_ * 2);
  short* kb   = (short*)alloc((size_t)BH_ * N_ * D_ * 2);
  short* vb   = (short*)alloc((size_t)BH_ * N_ * D_ * 2);    // reused as attn out
  short* vtb  = (short*)alloc((size_t)BH_ * D_ * N_ * 2);
  float* h    = (float*)alloc((size_t)MM * C_ * 4);
  short* hid  = (short*)alloc((size_t)MM * HID_ * 2);
  float* ppj  = (float*)alloc((size_t)2 * MM * C_ * 4);      // proj split-K partials
  float* pf2  = (float*)alloc((size_t)4 * MM * C_ * 4);      // fc2 split-K partials
  short* hln  = xln;    // xln dead after qkv gemm
  short* aout = vb;     // vb dead after transpose

  k_cvt4<<<6912, 256, 0, stream>>>(qkv_w, wq, proj_w, wp, fc1_w, wf1, fc2_w, wf2);

  k_ln<<<MM, 256, 0, stream>>>(x, n1w, n1b, xln);
  k_gemm_qkv<<<dim3(MM / 128, 3 * C_ / 128), 256, 0, stream>>>(xln, wq, qkv_b,
                                                               qb, kb, vb);
  k_trans_v<<<dim3(N_ / 64, BH_), 256, 0, stream>>>(vb, vtb);
  k_attn<<<dim3(N_ / 64, BH_), 256, 0, stream>>>(qb, kb, vtb, alibi, mask, aout);
  k_gemm_projs<<<dim3(MM / 128, C_ / 128, 2), 256, 0, stream>>>(aout, wp, ppj);
  k_proj_red<<<MM * C_ / 1024, 256, 0, stream>>>(ppj, proj_b, x, h);
  k_ln<<<MM, 256, 0, stream>>>(h, n2w, n2b, hln);
  k_gemm_fc1<<<dim3(MM / 128, HID_ / 128), 256, 0, stream>>>(hln, wf1, fc1_b, hid);
  k_gemm_fc2s<<<dim3(MM / 128, C_ / 128, 4), 256, 0, stream>>>(hid, wf2, pf2);
  k_fc2_red<<<MM * C_ / 1024, 256, 0, stream>>>(pf2, fc2_b, out);
}